// Round 6
// baseline (578.901 us; speedup 1.0000x reference)
//
#include <hip/hip_runtime.h>
#include <hip/hip_bf16.h>

#define NRULES 128
#define NH 256
#define NC 10
#define NF 256
#define BM 128

typedef __attribute__((ext_vector_type(8))) __bf16 bf16x8;
typedef __attribute__((ext_vector_type(4))) __bf16 bf16x4;
typedef __attribute__((ext_vector_type(4))) float f32x4;
typedef __attribute__((ext_vector_type(4))) int i32x4;

static __device__ __forceinline__ unsigned int f2bf_bits(float f) {
    unsigned int u = __float_as_uint(f);
    u += 0x7fffu + ((u >> 16) & 1u);
    return u >> 16;
}

static __device__ __forceinline__ float tanh_fast(float x) {
    float xc = fminf(fmaxf(x, -15.f), 15.f);
    float e = __expf(2.f * xc);
    return 1.f - 2.f * __builtin_amdgcn_rcpf(e + 1.f);
}

// ---------------------------------------------------------------------------
// Prep: W1 (256f x 256h f32) -> W1T (256h x 256f bf16),
//       W2 (256h x 128r f32) -> W2T (128r x 256h bf16). 64x64 LDS tiles.
// ---------------------------------------------------------------------------
__global__ __launch_bounds__(256) void prep_transpose(
    const float* __restrict__ W1, const float* __restrict__ W2,
    unsigned short* __restrict__ W1T, unsigned short* __restrict__ W2T)
{
    __shared__ float tile[64][65];
    const int b = blockIdx.x;
    const float* src;
    unsigned short* dst;
    int sstride;
    if (b < 16) {                      // W1: 4x4 tiles
        int ti = b >> 2, tj = b & 3;
        src = W1 + ti * 64 * 256 + tj * 64;  sstride = 256;
        dst = W1T + tj * 64 * 256 + ti * 64;
    } else {                           // W2: 4 row-tiles x 2 col-tiles
        int bb = b - 16;
        int ti = bb >> 1, tj = bb & 1;
        src = W2 + ti * 64 * 128 + tj * 64;  sstride = 128;
        dst = W2T + tj * 64 * 256 + ti * 64;
    }
    const int t = threadIdx.x;
    #pragma unroll
    for (int i = 0; i < 4; ++i) {
        int idx = i * 256 + t;
        int r = idx >> 4, c4 = (idx & 15) * 4;
        f32x4 v = *(const f32x4*)(src + r * sstride + c4);
        tile[r][c4 + 0] = v.x; tile[r][c4 + 1] = v.y;
        tile[r][c4 + 2] = v.z; tile[r][c4 + 3] = v.w;
    }
    __syncthreads();
    #pragma unroll
    for (int i = 0; i < 2; ++i) {
        int idx = i * 256 + t;
        int rr = idx >> 3, cc = (idx & 7) * 8;
        i32x4 pk;
        #pragma unroll
        for (int j = 0; j < 4; ++j) {
            unsigned int lo = f2bf_bits(tile[cc + 2 * j][rr]);
            unsigned int hi = f2bf_bits(tile[cc + 2 * j + 1][rr]);
            pk[j] = (int)(lo | (hi << 16));
        }
        *(i32x4*)(dst + rr * 256 + cc) = pk;   // 16B coalesced
    }
}

// ---------------------------------------------------------------------------
// Fused kernel. 512 threads (8 waves), BM=128.
// LDS: Xs 64KB (X bf16 -> H bf16 -> coverage f32, swizzled chunk^=(row&7))
//      Vs 8.5KB vote nibbles, lbuck 5KB class-bucket floats. Total 77.5KB
//      -> 2 blocks/CU.
// ---------------------------------------------------------------------------
__global__ __launch_bounds__(512, 4) void fused_mlp_attn(
    const float* __restrict__ x_lf, const float* __restrict__ x_l,
    const float* __restrict__ b1, const float* __restrict__ b2,
    const unsigned short* __restrict__ W1T, const unsigned short* __restrict__ W2T,
    float* __restrict__ out0, float* __restrict__ out1)
{
    __shared__ __align__(16) unsigned char smem[BM * 512 + BM * 68 + BM * 40];
    unsigned char* Xs = smem;                       // 128 x 512B
    unsigned char* Vs = smem + BM * 512;            // 128 x 68B
    float* lbuck = (float*)(smem + BM * 512 + BM * 68);  // 128 x 10 f32

    const int tid = threadIdx.x;
    const long e0 = (long)blockIdx.x * BM;

    // ---- zero the bucket table (covered by the first barrier) ----
    #pragma unroll
    for (int i = 0; i < 3; ++i) {
        int idx = i * 512 + tid;
        if (idx < BM * 10) lbuck[idx] = 0.f;
    }

    // ---- stage X: batched loads first (16 loads in flight), then convert ----
    f32x4 ra[8], rb[8];
    #pragma unroll
    for (int i = 0; i < 8; ++i) {
        int idx = i * 512 + tid;
        int e = idx >> 5;
        int c = idx & 31;
        const float* src = (c < 16) ? (x_lf + (e0 + e) * 128 + c * 8)
                                    : (x_l  + (e0 + e) * 128 + (c - 16) * 8);
        ra[i] = *(const f32x4*)src;
        rb[i] = *(const f32x4*)(src + 4);
    }
    #pragma unroll
    for (int i = 0; i < 8; ++i) {
        int idx = i * 512 + tid;
        int e = idx >> 5;
        int c = idx & 31;
        f32x4 a = ra[i], bq = rb[i];
        bf16x8 pk;
        pk[0] = (__bf16)a.x;  pk[1] = (__bf16)a.y;
        pk[2] = (__bf16)a.z;  pk[3] = (__bf16)a.w;
        pk[4] = (__bf16)bq.x; pk[5] = (__bf16)bq.y;
        pk[6] = (__bf16)bq.z; pk[7] = (__bf16)bq.w;
        *(bf16x8*)(Xs + e * 512 + ((c ^ (e & 7)) << 4)) = pk;
        if (c < 16) {                         // x_lf chunk: vote+1 nibbles
            unsigned int v = 0;
            v |= (unsigned int)((int)a.x  + 1);
            v |= (unsigned int)((int)a.y  + 1) << 4;
            v |= (unsigned int)((int)a.z  + 1) << 8;
            v |= (unsigned int)((int)a.w  + 1) << 12;
            v |= (unsigned int)((int)bq.x + 1) << 16;
            v |= (unsigned int)((int)bq.y + 1) << 20;
            v |= (unsigned int)((int)bq.z + 1) << 24;
            v |= (unsigned int)((int)bq.w + 1) << 28;
            *(unsigned int*)(Vs + e * 68 + c * 4) = v;
        }
    }
    __syncthreads();

    const int wv  = tid >> 6;                 // 8 waves
    const int lane = tid & 63;
    const int q   = lane >> 4;
    const int l15 = lane & 15;

    // ---- layer 1: H^T(256h x 128e) = W1T . X^T ; wave owns 32 hidden ----
    const int hb = wv * 32;
    f32x4 acc[2][8];
    #pragma unroll
    for (int mt = 0; mt < 2; ++mt)
        #pragma unroll
        for (int nt = 0; nt < 8; ++nt)
            acc[mt][nt] = (f32x4){0.f, 0.f, 0.f, 0.f};

    for (int kk = 0; kk < 8; ++kk) {
        const int k = kk * 32 + q * 8;
        bf16x8 af[2];
        #pragma unroll
        for (int mt = 0; mt < 2; ++mt)
            af[mt] = *(const bf16x8*)(W1T + (hb + mt * 16 + l15) * 256 + k);
        const int cc = kk * 4 + q;
        bf16x8 bfq[8];
        #pragma unroll
        for (int nt = 0; nt < 8; ++nt) {
            int e = nt * 16 + l15;
            bfq[nt] = *(const bf16x8*)(Xs + e * 512 + ((cc ^ (e & 7)) << 4));
        }
        #pragma unroll
        for (int mt = 0; mt < 2; ++mt)
            #pragma unroll
            for (int nt = 0; nt < 8; ++nt)
                acc[mt][nt] = __builtin_amdgcn_mfma_f32_16x16x32_bf16(
                    af[mt], bfq[nt], acc[mt][nt], 0, 0, 0);
    }

    // bias + tanh (in registers)
    #pragma unroll
    for (int mt = 0; mt < 2; ++mt) {
        f32x4 bv = *(const f32x4*)(b1 + hb + mt * 16 + q * 4);
        #pragma unroll
        for (int nt = 0; nt < 8; ++nt)
            #pragma unroll
            for (int j = 0; j < 4; ++j)
                acc[mt][nt][j] = tanh_fast(acc[mt][nt][j] + bv[j]);
    }

    __syncthreads();   // all waves done reading Xs; safe to overwrite with H

    // write H bf16 into Xs space: lane holds 4 consecutive hidden per example
    #pragma unroll
    for (int mt = 0; mt < 2; ++mt) {
        int h = hb + mt * 16 + q * 4;
        int c16 = h >> 3;
        int sub = (h & 4) << 1;              // 0 or 8 bytes within chunk
        #pragma unroll
        for (int nt = 0; nt < 8; ++nt) {
            int e = nt * 16 + l15;
            bf16x4 d;
            d[0] = (__bf16)acc[mt][nt][0]; d[1] = (__bf16)acc[mt][nt][1];
            d[2] = (__bf16)acc[mt][nt][2]; d[3] = (__bf16)acc[mt][nt][3];
            *(bf16x4*)(Xs + e * 512 + ((c16 ^ (e & 7)) << 4) + sub) = d;
        }
    }
    __syncthreads();

    // ---- layer 2: Z^T(128r x 128e) = W2T . H^T ; wave owns 16 examples ----
    const int eb = wv * 16;
    f32x4 acc2[8];
    #pragma unroll
    for (int mt = 0; mt < 8; ++mt)
        acc2[mt] = (f32x4){0.f, 0.f, 0.f, 0.f};

    for (int kk = 0; kk < 8; ++kk) {
        const int k = kk * 32 + q * 8;
        bf16x8 af2[8];
        #pragma unroll
        for (int mt = 0; mt < 8; ++mt)
            af2[mt] = *(const bf16x8*)(W2T + (mt * 16 + l15) * 256 + k);
        const int cc = kk * 4 + q;
        int e = eb + l15;
        bf16x8 bf2 = *(const bf16x8*)(Xs + e * 512 + ((cc ^ (e & 7)) << 4));
        #pragma unroll
        for (int mt = 0; mt < 8; ++mt)
            acc2[mt] = __builtin_amdgcn_mfma_f32_16x16x32_bf16(
                af2[mt], bf2, acc2[mt], 0, 0, 0);
    }

    // ---- epilogue part 1: softmax + coverage in regs + bucket atomics ----
    const int e = eb + l15;
    {
        #pragma unroll
        for (int mt = 0; mt < 8; ++mt) {
            f32x4 bv = *(const f32x4*)(b2 + mt * 16 + q * 4);
            acc2[mt] += bv;
        }

        int vt[8];
        #pragma unroll
        for (int mt = 0; mt < 8; ++mt)
            vt[mt] = *(const unsigned short*)(Vs + e * 68 + mt * 8 + q * 2);

        float m = -3.4e38f;
        #pragma unroll
        for (int mt = 0; mt < 8; ++mt)
            #pragma unroll
            for (int j = 0; j < 4; ++j)
                m = fmaxf(m, acc2[mt][j]);
        m = fmaxf(m, __shfl_xor(m, 16));
        m = fmaxf(m, __shfl_xor(m, 32));

        float s = 0.f;
        #pragma unroll
        for (int mt = 0; mt < 8; ++mt)
            #pragma unroll
            for (int j = 0; j < 4; ++j) {
                float p = __expf(acc2[mt][j] - m);
                acc2[mt][j] = p;
                s += p;
            }
        s += __shfl_xor(s, 16);
        s += __shfl_xor(s, 32);
        const float inv = __builtin_amdgcn_rcpf(s);

        // scale to scores; coverage kept in acc2; buckets via LDS atomics
        #pragma unroll
        for (int mt = 0; mt < 8; ++mt) {
            int u = vt[mt];
            #pragma unroll
            for (int j = 0; j < 4; ++j) {
                float sc = acc2[mt][j] * inv;
                int v = (u >> (4 * j)) & 15;       // vote+1, 0 = abstain
                acc2[mt][j] = (v != 0) ? sc : 0.f;
                if (v != 0) atomicAdd(&lbuck[e * 10 + v - 1], sc);
            }
        }
    }
    __syncthreads();   // all L2 Xs reads done + all bucket atomics issued

    // ---- epilogue part 2: coverage -> Xs (f32, swizzled) ----
    #pragma unroll
    for (int mt = 0; mt < 8; ++mt)
        *(f32x4*)(Xs + e * 512 + (((mt * 4 + q) ^ (e & 7)) << 4)) = acc2[mt];
    __syncthreads();

    // ---- epilogue part 3: coalesced streaming of out1 + out0 logsumexp ----
    #pragma unroll
    for (int i = 0; i < 8; ++i) {
        int idx = i * 512 + tid;                    // 16B chunk id, 0..4095
        int row = idx >> 5;
        int ch  = idx & 31;
        f32x4 vv = *(const f32x4*)(Xs + row * 512 + ((ch ^ (row & 7)) << 4));
        __builtin_nontemporal_store(vv, (f32x4*)(out1 + e0 * 128 + (long)idx * 4));
    }

    if (tid < BM) {
        float b[NC];
        #pragma unroll
        for (int c = 0; c < NC; ++c) b[c] = lbuck[tid * 10 + c];
        float m10 = b[0];
        #pragma unroll
        for (int c = 1; c < NC; ++c) m10 = fmaxf(m10, b[c]);
        float se = 0.f;
        #pragma unroll
        for (int c = 0; c < NC; ++c) se += __expf(b[c] - m10);
        const float lse = m10 + __logf(se);
        float* o = out0 + (e0 + tid) * 10;
        #pragma unroll
        for (int c = 0; c < NC; ++c) o[c] = b[c] - lse;
    }
}

extern "C" void kernel_launch(void* const* d_in, const int* in_sizes, int n_in,
                              void* d_out, int out_size, void* d_ws, size_t ws_size,
                              hipStream_t stream)
{
    const float* x_lf = (const float*)d_in[0];
    const float* x_l  = (const float*)d_in[1];
    const float* W1   = (const float*)d_in[2];
    const float* b1   = (const float*)d_in[3];
    const float* W2   = (const float*)d_in[4];
    const float* b2   = (const float*)d_in[5];
    const int n = in_sizes[0] / NRULES;            // 262144
    float* out0 = (float*)d_out;                   // (n, 10) log-softmax
    float* out1 = out0 + (long)n * NC;             // (n, 128) coverage
    unsigned short* W1T = (unsigned short*)d_ws;   // 256x256 bf16
    unsigned short* W2T = W1T + NH * NF;           // 128x256 bf16

    prep_transpose<<<24, 256, 0, stream>>>(W1, W2, W1T, W2T);
    fused_mlp_attn<<<n / BM, 512, 0, stream>>>(x_lf, x_l, b1, b2, W1T, W2T,
                                               out0, out1);
}

// Round 7
// 483.216 us; speedup vs baseline: 1.1980x; 1.1980x over previous
//
#include <hip/hip_runtime.h>
#include <hip/hip_bf16.h>

#define NRULES 128
#define NH 256
#define NC 10
#define NF 256
#define BM 64

typedef __attribute__((ext_vector_type(8))) __bf16 bf16x8;
typedef __attribute__((ext_vector_type(4))) __bf16 bf16x4;
typedef __attribute__((ext_vector_type(4))) float f32x4;
typedef __attribute__((ext_vector_type(4))) int i32x4;

static __device__ __forceinline__ unsigned int f2bf_bits(float f) {
    unsigned int u = __float_as_uint(f);
    u += 0x7fffu + ((u >> 16) & 1u);
    return u >> 16;
}

static __device__ __forceinline__ float tanh_fast(float x) {
    float xc = fminf(fmaxf(x, -15.f), 15.f);
    float e = __expf(2.f * xc);
    return 1.f - 2.f * __builtin_amdgcn_rcpf(e + 1.f);
}

// ---------------------------------------------------------------------------
// Prep: W1 (256f x 256h f32) -> W1T (256h x 256f bf16),
//       W2 (256h x 128r f32) -> W2T (128r x 256h bf16). 64x64 LDS tiles.
// ---------------------------------------------------------------------------
__global__ __launch_bounds__(256) void prep_transpose(
    const float* __restrict__ W1, const float* __restrict__ W2,
    unsigned short* __restrict__ W1T, unsigned short* __restrict__ W2T)
{
    __shared__ float tile[64][65];
    const int b = blockIdx.x;
    const float* src;
    unsigned short* dst;
    int sstride;
    if (b < 16) {                      // W1: 4x4 tiles
        int ti = b >> 2, tj = b & 3;
        src = W1 + ti * 64 * 256 + tj * 64;  sstride = 256;
        dst = W1T + tj * 64 * 256 + ti * 64;
    } else {                           // W2: 4 row-tiles x 2 col-tiles
        int bb = b - 16;
        int ti = bb >> 1, tj = bb & 1;
        src = W2 + ti * 64 * 128 + tj * 64;  sstride = 128;
        dst = W2T + tj * 64 * 256 + ti * 64;
    }
    const int t = threadIdx.x;
    #pragma unroll
    for (int i = 0; i < 4; ++i) {
        int idx = i * 256 + t;
        int r = idx >> 4, c4 = (idx & 15) * 4;
        f32x4 v = *(const f32x4*)(src + r * sstride + c4);
        tile[r][c4 + 0] = v.x; tile[r][c4 + 1] = v.y;
        tile[r][c4 + 2] = v.z; tile[r][c4 + 3] = v.w;
    }
    __syncthreads();
    #pragma unroll
    for (int i = 0; i < 2; ++i) {
        int idx = i * 256 + t;
        int rr = idx >> 3, cc = (idx & 7) * 8;
        i32x4 pk;
        #pragma unroll
        for (int j = 0; j < 4; ++j) {
            unsigned int lo = f2bf_bits(tile[cc + 2 * j][rr]);
            unsigned int hi = f2bf_bits(tile[cc + 2 * j + 1][rr]);
            pk[j] = (int)(lo | (hi << 16));
        }
        *(i32x4*)(dst + rr * 256 + cc) = pk;   // 16B coalesced
    }
}

// ---------------------------------------------------------------------------
// Fused kernel. 256 threads (4 waves), BM=64.
// LDS: Xs 32KB (X bf16 -> H bf16, swizzled chunk^=(row&7)) + Vs 4.25KB votes
//      = 36.25KB -> 4 blocks/CU (phase-staggered for latency hiding).
// ---------------------------------------------------------------------------
__global__ __launch_bounds__(256, 4) void fused_mlp_attn(
    const float* __restrict__ x_lf, const float* __restrict__ x_l,
    const float* __restrict__ b1, const float* __restrict__ b2,
    const unsigned short* __restrict__ W1T, const unsigned short* __restrict__ W2T,
    float* __restrict__ out0, float* __restrict__ out1)
{
    __shared__ __align__(16) unsigned char smem[BM * 512 + BM * 68];
    unsigned char* Xs = smem;                 // 64 rows x 512B, also Hs later
    unsigned char* Vs = smem + BM * 512;      // 64 rows x 68B vote nibbles

    const int tid = threadIdx.x;
    const long e0 = (long)blockIdx.x * BM;

    // ---- stage X: fp32 -> bf16 into LDS (swizzled), pack votes ----
    #pragma unroll
    for (int i = 0; i < 8; ++i) {
        int idx = i * 256 + tid;
        int e = idx >> 5;
        int c = idx & 31;                     // 16B chunk within row
        const float* src = (c < 16) ? (x_lf + (e0 + e) * 128 + c * 8)
                                    : (x_l  + (e0 + e) * 128 + (c - 16) * 8);
        f32x4 a  = *(const f32x4*)src;
        f32x4 bq = *(const f32x4*)(src + 4);
        bf16x8 pk;
        pk[0] = (__bf16)a.x;  pk[1] = (__bf16)a.y;
        pk[2] = (__bf16)a.z;  pk[3] = (__bf16)a.w;
        pk[4] = (__bf16)bq.x; pk[5] = (__bf16)bq.y;
        pk[6] = (__bf16)bq.z; pk[7] = (__bf16)bq.w;
        *(bf16x8*)(Xs + e * 512 + ((c ^ (e & 7)) << 4)) = pk;
        if (c < 16) {                         // x_lf chunk: vote+1 nibbles
            unsigned int v = 0;
            v |= (unsigned int)((int)a.x  + 1);
            v |= (unsigned int)((int)a.y  + 1) << 4;
            v |= (unsigned int)((int)a.z  + 1) << 8;
            v |= (unsigned int)((int)a.w  + 1) << 12;
            v |= (unsigned int)((int)bq.x + 1) << 16;
            v |= (unsigned int)((int)bq.y + 1) << 20;
            v |= (unsigned int)((int)bq.z + 1) << 24;
            v |= (unsigned int)((int)bq.w + 1) << 28;
            *(unsigned int*)(Vs + e * 68 + c * 4) = v;
        }
    }
    __syncthreads();

    const int wv  = tid >> 6;                 // 4 waves
    const int lane = tid & 63;
    const int q   = lane >> 4;
    const int l15 = lane & 15;

    // ---- layer 1: H^T(256h x 64e) = W1T . X^T ; wave owns 64 hidden ----
    const int hb = wv * 64;
    f32x4 acc[4][4];
    #pragma unroll
    for (int mt = 0; mt < 4; ++mt)
        #pragma unroll
        for (int nt = 0; nt < 4; ++nt)
            acc[mt][nt] = (f32x4){0.f, 0.f, 0.f, 0.f};

    for (int kk = 0; kk < 8; ++kk) {
        const int k = kk * 32 + q * 8;
        bf16x8 af[4];
        #pragma unroll
        for (int mt = 0; mt < 4; ++mt)
            af[mt] = *(const bf16x8*)(W1T + (hb + mt * 16 + l15) * 256 + k);
        const int cc = kk * 4 + q;
        bf16x8 bfq[4];
        #pragma unroll
        for (int nt = 0; nt < 4; ++nt) {
            int e = nt * 16 + l15;
            bfq[nt] = *(const bf16x8*)(Xs + e * 512 + ((cc ^ (e & 7)) << 4));
        }
        #pragma unroll
        for (int mt = 0; mt < 4; ++mt)
            #pragma unroll
            for (int nt = 0; nt < 4; ++nt)
                acc[mt][nt] = __builtin_amdgcn_mfma_f32_16x16x32_bf16(
                    af[mt], bfq[nt], acc[mt][nt], 0, 0, 0);
    }

    // bias + tanh (in registers)
    #pragma unroll
    for (int mt = 0; mt < 4; ++mt) {
        f32x4 bv = *(const f32x4*)(b1 + hb + mt * 16 + q * 4);
        #pragma unroll
        for (int nt = 0; nt < 4; ++nt)
            #pragma unroll
            for (int j = 0; j < 4; ++j)
                acc[mt][nt][j] = tanh_fast(acc[mt][nt][j] + bv[j]);
    }

    __syncthreads();   // all waves done reading Xs; safe to overwrite with H

    // write H bf16 into Xs space: lane holds 4 consecutive hidden per example
    #pragma unroll
    for (int mt = 0; mt < 4; ++mt) {
        int h = hb + mt * 16 + q * 4;
        int c16 = h >> 3;
        int sub = (h & 4) << 1;              // 0 or 8 bytes within chunk
        #pragma unroll
        for (int nt = 0; nt < 4; ++nt) {
            int e = nt * 16 + l15;
            bf16x4 d;
            d[0] = (__bf16)acc[mt][nt][0]; d[1] = (__bf16)acc[mt][nt][1];
            d[2] = (__bf16)acc[mt][nt][2]; d[3] = (__bf16)acc[mt][nt][3];
            *(bf16x4*)(Xs + e * 512 + ((c16 ^ (e & 7)) << 4) + sub) = d;
        }
    }
    __syncthreads();

    // ---- layer 2: Z^T(128r x 64e) = W2T . H^T ; wave owns 16 examples ----
    const int eb = wv * 16;
    f32x4 acc2[8];
    #pragma unroll
    for (int mt = 0; mt < 8; ++mt)
        acc2[mt] = (f32x4){0.f, 0.f, 0.f, 0.f};

    for (int kk = 0; kk < 8; ++kk) {
        const int k = kk * 32 + q * 8;
        bf16x8 af2[8];
        #pragma unroll
        for (int mt = 0; mt < 8; ++mt)
            af2[mt] = *(const bf16x8*)(W2T + (mt * 16 + l15) * 256 + k);
        const int cc = kk * 4 + q;
        int e = eb + l15;
        bf16x8 bf2 = *(const bf16x8*)(Xs + e * 512 + ((cc ^ (e & 7)) << 4));
        #pragma unroll
        for (int mt = 0; mt < 8; ++mt)
            acc2[mt] = __builtin_amdgcn_mfma_f32_16x16x32_bf16(
                af2[mt], bf2, acc2[mt], 0, 0, 0);
    }

    // ---- epilogue: 4 lanes {l15, q=0..3} hold the 128 rules of example e ----
    {
        const int e = eb + l15;

        #pragma unroll
        for (int mt = 0; mt < 8; ++mt) {
            f32x4 bv = *(const f32x4*)(b2 + mt * 16 + q * 4);
            acc2[mt] += bv;
        }

        int vt[8];
        #pragma unroll
        for (int mt = 0; mt < 8; ++mt)
            vt[mt] = *(const unsigned short*)(Vs + e * 68 + mt * 8 + q * 2);

        float m = -3.4e38f;
        #pragma unroll
        for (int mt = 0; mt < 8; ++mt)
            #pragma unroll
            for (int j = 0; j < 4; ++j)
                m = fmaxf(m, acc2[mt][j]);
        m = fmaxf(m, __shfl_xor(m, 16));
        m = fmaxf(m, __shfl_xor(m, 32));

        float s = 0.f;
        #pragma unroll
        for (int mt = 0; mt < 8; ++mt)
            #pragma unroll
            for (int j = 0; j < 4; ++j) {
                float p = __expf(acc2[mt][j] - m);
                acc2[mt][j] = p;
                s += p;
            }
        s += __shfl_xor(s, 16);
        s += __shfl_xor(s, 32);
        const float inv = __builtin_amdgcn_rcpf(s);

        float bucket[NC];
        #pragma unroll
        for (int c = 0; c < NC; ++c) bucket[c] = 0.f;

        #pragma unroll
        for (int mt = 0; mt < 8; ++mt) {
            int u = vt[mt];
            f32x4 cov;
            #pragma unroll
            for (int j = 0; j < 4; ++j) {
                float sc = acc2[mt][j] * inv;
                int v = (u >> (4 * j)) & 15;       // vote+1, 0 = abstain
                cov[j] = (v != 0) ? sc : 0.f;
                #pragma unroll
                for (int c = 0; c < NC; ++c)
                    bucket[c] += (v == c + 1) ? sc : 0.f;
            }
            *(f32x4*)(out1 + (e0 + e) * 128 + mt * 16 + q * 4) = cov;
        }

        #pragma unroll
        for (int c = 0; c < NC; ++c) {
            bucket[c] += __shfl_xor(bucket[c], 16);
            bucket[c] += __shfl_xor(bucket[c], 32);
        }

        float m10 = bucket[0];
        #pragma unroll
        for (int c = 1; c < NC; ++c) m10 = fmaxf(m10, bucket[c]);
        float se = 0.f;
        #pragma unroll
        for (int c = 0; c < NC; ++c) se += __expf(bucket[c] - m10);
        const float lse = m10 + __logf(se);

        if (q == 0) {
            float* o = out0 + (e0 + e) * 10;
            #pragma unroll
            for (int c = 0; c < NC; ++c) o[c] = bucket[c] - lse;
        }
    }
}

extern "C" void kernel_launch(void* const* d_in, const int* in_sizes, int n_in,
                              void* d_out, int out_size, void* d_ws, size_t ws_size,
                              hipStream_t stream)
{
    const float* x_lf = (const float*)d_in[0];
    const float* x_l  = (const float*)d_in[1];
    const float* W1   = (const float*)d_in[2];
    const float* b1   = (const float*)d_in[3];
    const float* W2   = (const float*)d_in[4];
    const float* b2   = (const float*)d_in[5];
    const int n = in_sizes[0] / NRULES;            // 262144
    float* out0 = (float*)d_out;                   // (n, 10) log-softmax
    float* out1 = out0 + (long)n * NC;             // (n, 128) coverage
    unsigned short* W1T = (unsigned short*)d_ws;   // 256x256 bf16
    unsigned short* W2T = W1T + NH * NF;           // 128x256 bf16

    prep_transpose<<<24, 256, 0, stream>>>(W1, W2, W1T, W2T);
    fused_mlp_attn<<<n / BM, 256, 0, stream>>>(x_lf, x_l, b1, b2, W1T, W2T,
                                               out0, out1);
}

// Round 8
// 464.047 us; speedup vs baseline: 1.2475x; 1.0413x over previous
//
#include <hip/hip_runtime.h>
#include <hip/hip_bf16.h>

#define NRULES 128
#define NH 256
#define NC 10
#define NF 256
#define BM 64

typedef __attribute__((ext_vector_type(8))) __bf16 bf16x8;
typedef __attribute__((ext_vector_type(4))) __bf16 bf16x4;
typedef __attribute__((ext_vector_type(4))) float f32x4;

static __device__ __forceinline__ float tanh_fast(float x) {
    float xc = fminf(fmaxf(x, -15.f), 15.f);
    float e = __expf(2.f * xc);
    return 1.f - 2.f * __builtin_amdgcn_rcpf(e + 1.f);
}

// ---------------------------------------------------------------------------
// Prep: fragment-ordered bf16 weights.
//  W1 (256f x 256h f32, [f][h]) -> W1s[kkq=f/8][h][j=f%8]   (32 x 256 x 8 bf16)
//  W2 (256h x 128r f32, [h][r]) -> W2s[kkq=h/8][r][j=h%8]   (32 x 128 x 8 bf16)
// A-fragment load for MFMA k-slice kkq is then 16 lanes x 16B CONTIGUOUS.
// ---------------------------------------------------------------------------
__global__ __launch_bounds__(256) void prep_weights(
    const float* __restrict__ W1, const float* __restrict__ W2,
    unsigned short* __restrict__ W1s, unsigned short* __restrict__ W2s)
{
    const int b = blockIdx.x, t = threadIdx.x;
    if (b < 32) {                       // W1: kkq = b, h = t
        bf16x8 pk;
        #pragma unroll
        for (int j = 0; j < 8; ++j)
            pk[j] = (__bf16)W1[(b * 8 + j) * 256 + t];
        *(bf16x8*)(W1s + (b * 256 + t) * 8) = pk;
    } else {                            // W2: 2 kkq per block
        int kkq = (b - 32) * 2 + (t >> 7);
        int r = t & 127;
        bf16x8 pk;
        #pragma unroll
        for (int j = 0; j < 8; ++j)
            pk[j] = (__bf16)W2[(kkq * 8 + j) * 128 + r];
        *(bf16x8*)(W2s + (kkq * 128 + r) * 8) = pk;
    }
}

// ---------------------------------------------------------------------------
// Fused kernel, NO X staging: B-fragments loaded straight from global fp32
// and converted in-register. LDS holds only H (32KB, swizzled). One barrier.
// 256 threads (4 waves), BM=64, grid 4096.
// ---------------------------------------------------------------------------
__global__ __launch_bounds__(256) void fused_mlp_attn(
    const float* __restrict__ x_lf, const float* __restrict__ x_l,
    const float* __restrict__ b1, const float* __restrict__ b2,
    const unsigned short* __restrict__ W1s, const unsigned short* __restrict__ W2s,
    float* __restrict__ out0, float* __restrict__ out1)
{
    __shared__ __align__(16) unsigned char Hs[BM * 512];   // H bf16, swizzled

    const int tid = threadIdx.x;
    const long e0 = (long)blockIdx.x * BM;
    const int wv  = tid >> 6;                 // 4 waves
    const int lane = tid & 63;
    const int q   = lane >> 4;
    const int l15 = lane & 15;

    // ---- layer 1: H^T(256h x 64e) = W1 . X^T ; wave owns 64 hidden ----
    const int hb = wv * 64;
    f32x4 acc[4][4];
    #pragma unroll
    for (int mt = 0; mt < 4; ++mt)
        #pragma unroll
        for (int nt = 0; nt < 4; ++nt)
            acc[mt][nt] = (f32x4){0.f, 0.f, 0.f, 0.f};

    for (int kk = 0; kk < 8; ++kk) {
        // A: weights, contiguous 16B/lane from fragment-ordered W1s (L2-hot)
        const unsigned short* wbase = W1s + ((kk * 4 + q) * 256 + hb + l15) * 8;
        bf16x8 af[4];
        #pragma unroll
        for (int mt = 0; mt < 4; ++mt)
            af[mt] = *(const bf16x8*)(wbase + mt * 16 * 8);

        // B: X fragments direct from global fp32 (k<128 -> x_lf, else x_l)
        const float* xsrc = (kk < 4) ? (x_lf + (kk * 32 + q * 8))
                                     : (x_l + ((kk - 4) * 32 + q * 8));
        bf16x8 xb[4];
        #pragma unroll
        for (int nt = 0; nt < 4; ++nt) {
            const float* p = xsrc + (e0 + nt * 16 + l15) * 128;
            f32x4 a  = *(const f32x4*)p;
            f32x4 bq = *(const f32x4*)(p + 4);
            bf16x8 pk;
            pk[0] = (__bf16)a.x;  pk[1] = (__bf16)a.y;
            pk[2] = (__bf16)a.z;  pk[3] = (__bf16)a.w;
            pk[4] = (__bf16)bq.x; pk[5] = (__bf16)bq.y;
            pk[6] = (__bf16)bq.z; pk[7] = (__bf16)bq.w;
            xb[nt] = pk;
        }
        #pragma unroll
        for (int mt = 0; mt < 4; ++mt)
            #pragma unroll
            for (int nt = 0; nt < 4; ++nt)
                acc[mt][nt] = __builtin_amdgcn_mfma_f32_16x16x32_bf16(
                    af[mt], xb[nt], acc[mt][nt], 0, 0, 0);
    }

    // bias + tanh (in registers)
    #pragma unroll
    for (int mt = 0; mt < 4; ++mt) {
        f32x4 bv = *(const f32x4*)(b1 + hb + mt * 16 + q * 4);
        #pragma unroll
        for (int nt = 0; nt < 4; ++nt)
            #pragma unroll
            for (int j = 0; j < 4; ++j)
                acc[mt][nt][j] = tanh_fast(acc[mt][nt][j] + bv[j]);
    }

    // write H bf16 into LDS: lane holds 4 consecutive hidden per example
    #pragma unroll
    for (int mt = 0; mt < 4; ++mt) {
        int h = hb + mt * 16 + q * 4;
        int c16 = h >> 3;
        int sub = (h & 4) << 1;              // 0 or 8 bytes within chunk
        #pragma unroll
        for (int nt = 0; nt < 4; ++nt) {
            int e = nt * 16 + l15;
            bf16x4 d;
            d[0] = (__bf16)acc[mt][nt][0]; d[1] = (__bf16)acc[mt][nt][1];
            d[2] = (__bf16)acc[mt][nt][2]; d[3] = (__bf16)acc[mt][nt][3];
            *(bf16x4*)(Hs + e * 512 + ((c16 ^ (e & 7)) << 4) + sub) = d;
        }
    }
    __syncthreads();                          // the ONLY barrier

    // ---- layer 2: Z^T(128r x 64e) = W2 . H^T ; wave owns 16 examples ----
    const int eb = wv * 16;
    f32x4 acc2[8];
    #pragma unroll
    for (int mt = 0; mt < 8; ++mt)
        acc2[mt] = (f32x4){0.f, 0.f, 0.f, 0.f};

    for (int kk = 0; kk < 8; ++kk) {
        const unsigned short* wbase = W2s + ((kk * 4 + q) * 128 + l15) * 8;
        bf16x8 af2[8];
        #pragma unroll
        for (int mt = 0; mt < 8; ++mt)
            af2[mt] = *(const bf16x8*)(wbase + mt * 16 * 8);
        const int cc = kk * 4 + q;
        int e = eb + l15;
        bf16x8 hf = *(const bf16x8*)(Hs + e * 512 + ((cc ^ (e & 7)) << 4));
        #pragma unroll
        for (int mt = 0; mt < 8; ++mt)
            acc2[mt] = __builtin_amdgcn_mfma_f32_16x16x32_bf16(
                af2[mt], hf, acc2[mt], 0, 0, 0);
    }

    // ---- epilogue: 4 lanes {l15, q=0..3} hold the 128 rules of example e ----
    {
        const int e = eb + l15;

        #pragma unroll
        for (int mt = 0; mt < 8; ++mt) {
            f32x4 bv = *(const f32x4*)(b2 + mt * 16 + q * 4);
            acc2[mt] += bv;
        }

        // votes: re-read x_lf straight from global (L2-hot, 16 rows x 64B)
        f32x4 vr[8];
        #pragma unroll
        for (int mt = 0; mt < 8; ++mt)
            vr[mt] = *(const f32x4*)(x_lf + (e0 + e) * 128 + mt * 16 + q * 4);

        float m = -3.4e38f;
        #pragma unroll
        for (int mt = 0; mt < 8; ++mt)
            #pragma unroll
            for (int j = 0; j < 4; ++j)
                m = fmaxf(m, acc2[mt][j]);
        m = fmaxf(m, __shfl_xor(m, 16));
        m = fmaxf(m, __shfl_xor(m, 32));

        float s = 0.f;
        #pragma unroll
        for (int mt = 0; mt < 8; ++mt)
            #pragma unroll
            for (int j = 0; j < 4; ++j) {
                float p = __expf(acc2[mt][j] - m);
                acc2[mt][j] = p;
                s += p;
            }
        s += __shfl_xor(s, 16);
        s += __shfl_xor(s, 32);
        const float inv = __builtin_amdgcn_rcpf(s);

        float bucket[NC];
        #pragma unroll
        for (int c = 0; c < NC; ++c) bucket[c] = 0.f;

        #pragma unroll
        for (int mt = 0; mt < 8; ++mt) {
            f32x4 cov;
            #pragma unroll
            for (int j = 0; j < 4; ++j) {
                float sc = acc2[mt][j] * inv;
                int v = (int)vr[mt][j];            // -1 = abstain, 0..9 class
                cov[j] = (v >= 0) ? sc : 0.f;
                #pragma unroll
                for (int c = 0; c < NC; ++c)
                    bucket[c] += (v == c) ? sc : 0.f;
            }
            *(f32x4*)(out1 + (e0 + e) * 128 + mt * 16 + q * 4) = cov;
        }

        #pragma unroll
        for (int c = 0; c < NC; ++c) {
            bucket[c] += __shfl_xor(bucket[c], 16);
            bucket[c] += __shfl_xor(bucket[c], 32);
        }

        float m10 = bucket[0];
        #pragma unroll
        for (int c = 1; c < NC; ++c) m10 = fmaxf(m10, bucket[c]);
        float se = 0.f;
        #pragma unroll
        for (int c = 0; c < NC; ++c) se += __expf(bucket[c] - m10);
        const float lse = m10 + __logf(se);

        if (q == 0) {
            float* o = out0 + (e0 + e) * 10;
            #pragma unroll
            for (int c = 0; c < NC; ++c) o[c] = bucket[c] - lse;
        }
    }
}

extern "C" void kernel_launch(void* const* d_in, const int* in_sizes, int n_in,
                              void* d_out, int out_size, void* d_ws, size_t ws_size,
                              hipStream_t stream)
{
    const float* x_lf = (const float*)d_in[0];
    const float* x_l  = (const float*)d_in[1];
    const float* W1   = (const float*)d_in[2];
    const float* b1   = (const float*)d_in[3];
    const float* W2   = (const float*)d_in[4];
    const float* b2   = (const float*)d_in[5];
    const int n = in_sizes[0] / NRULES;            // 262144
    float* out0 = (float*)d_out;                   // (n, 10) log-softmax
    float* out1 = out0 + (long)n * NC;             // (n, 128) coverage
    unsigned short* W1s = (unsigned short*)d_ws;   // 32x256x8 bf16
    unsigned short* W2s = W1s + NH * NF;           // 32x128x8 bf16

    prep_weights<<<48, 256, 0, stream>>>(W1, W2, W1s, W2s);
    fused_mlp_attn<<<n / BM, 256, 0, stream>>>(x_lf, x_l, b1, b2, W1s, W2s,
                                               out0, out1);
}